// Round 4
// baseline (24.640 us; speedup 1.0000x reference)
//
#include <hip/hip_runtime.h>
#include <math.h>

#define NB    512
#define DXN   100
#define MROW  128
#define TC    130
#define RS    64      // rows per block
#define CS    128     // cols per block
#define BT    512
#define KP    128     // padded K
#define AP    136     // LDS row stride (shorts) for A/B bf16 tiles
#define ALP   132     // LDS row stride (floats) for alpha
#define T0f   (-5.0f)
#define Hf    (10.0f / 99.0f)
#define LOG2E 1.4426950408889634f
#define WLO   42
#define WHI   67
#define WN    (WHI - WLO + 1)   // 26

typedef __attribute__((ext_vector_type(8))) short  short8;
typedef __attribute__((ext_vector_type(4))) float  f32x4;

__device__ __forceinline__ float Tval(int t) { return T0f + Hf * (float)t; }

__device__ __forceinline__ unsigned short bf16_rne(float x) {
    unsigned u = __float_as_uint(x);
    return (unsigned short)((u + 0x7FFF + ((u >> 16) & 1)) >> 16);
}
__device__ __forceinline__ float bf16_to_f(unsigned short h) {
    return __uint_as_float(((unsigned)h) << 16);
}

// ONE fused kernel: theta -> f -> dw -> Z, phi recomputed per block, MFMA GEMM, out.
// Block covers out[rowslab*64 .. +64][colslab*128 .. +128].
__global__ __launch_bounds__(BT) void fused_kernel(
    const float* __restrict__ theta,
    const float* __restrict__ mu,
    const float* __restrict__ sigma,
    float* __restrict__ out, int Bn)
{
    __shared__ float s_alpha[RS][ALP];            // 33 KB
    __shared__ float s_muc[RS], s_negth1[RS], s_invZ[RS];
    __shared__ float s_f[RS][WN];                 // 6.5 KB
    __shared__ float s_dwf[RS][DXN];              // 25 KB
    __shared__ unsigned short sAh[RS * AP];       // 17 KB
    __shared__ unsigned short sAl[RS * AP];       // 17 KB
    __shared__ unsigned short sBh[CS * AP];       // 34 KB   (total ~134 KB)

    const int tid = threadIdx.x;
    const int bid = blockIdx.x;
    const int rowslab = bid >> 2;
    const int colslab = bid & 3;
    const int b0 = rowslab * RS;
    const int c0 = colslab * CS;

    // Issue phi parameters early (consumed in Phase 2b).
    const int pcol = tid >> 2;                    // 0..127
    const int pk0  = (tid & 3) * 32;
    const float mun = mu[c0 + pcol];
    const float sgn = sigma[c0 + pcol];

    // ---- Phase 1: stage 64 theta rows (th0/th1 parked in s_muc/s_negth1) ----
    for (int i = tid; i < RS * TC; i += BT) {
        int r = i / TC, c = i - r * TC;
        int br = b0 + r; if (br >= Bn) br = Bn - 1;
        float v = theta[br * TC + c];
        if (c >= 2)      s_alpha[r][c - 2] = v;
        else if (c == 0) s_muc[r] = v;            // temp theta0
        else             s_negth1[r] = v;         // temp theta1
    }
    __syncthreads();

    // ---- Phase 2a: per-row scalars ----
    if (tid < RS) {
        float th1 = s_negth1[tid];                // <= -0.5
        s_muc[tid]    = s_muc[tid] * (-0.5f / th1);
        s_negth1[tid] = -th1;
    }

    // ---- Phase 2b: phi B-slab, bf16 hi, [col][k] k-contig, direct eval (exact) ----
    {
        const float inv_s = 1.0f / sgn;
        const float scale = 0.3989422804014327f * inv_s;
        const float Lh = 0.5f * LOG2E;
        #pragma unroll
        for (int g = 0; g < 4; ++g) {
            short8 pk;
            #pragma unroll
            for (int j = 0; j < 8; ++j) {
                int k = pk0 + g * 8 + j;
                float p = 0.0f;
                if (k < DXN) {
                    float u = (mun - Tval(k)) * inv_s;
                    p = scale * __builtin_amdgcn_exp2f(-Lh * u * u);
                }
                pk[j] = (short)bf16_rne(p);
            }
            *(short8*)&sBh[pcol * AP + pk0 + g * 8] = pk;
        }
    }

    // ---- Phase 3: f(r,t) on K-active window; exp2 recurrence, exact restart /16 ----
    for (int task = tid; task < RS * WN; task += BT) {
        int r = task / WN;
        int t = WLO + (task - r * WN);
        float T = Tval(t);
        const float C2 = 50.0f * LOG2E;
        const float dj = 1.0f / 127.0f;
        const float cc = -2.0f * C2 * dj * dj;
        const float* al = s_alpha[r];
        float f = 0.0f;
        #pragma unroll
        for (int j0 = 0; j0 < MROW; j0 += 16) {
            float d0 = (float)j0 * dj - T;
            float a  = -C2 * d0 * d0;
            float bb = -C2 * dj * (2.0f * d0 + dj);
            #pragma unroll
            for (int q = 0; q < 4; ++q) {
                float4 av = *(const float4*)&al[j0 + 4 * q];
                f += av.x * __builtin_amdgcn_exp2f(a); a += bb; bb += cc;
                f += av.y * __builtin_amdgcn_exp2f(a); a += bb; bb += cc;
                f += av.z * __builtin_amdgcn_exp2f(a); a += bb; bb += cc;
                f += av.w * __builtin_amdgcn_exp2f(a); a += bb; bb += cc;
            }
        }
        s_f[r][t - WLO] = f;
    }
    __syncthreads();

    // ---- Phase 4: dw fp32 + bf16 hi/lo A-tile (t>=100 zero pad), wave-contig in t ----
    for (int task = tid; task < RS * KP; task += BT) {
        int t = task & 127, r = task >> 7;
        float dw = 0.0f;
        if (t < DXN) {
            float f = (t >= WLO && t <= WHI) ? s_f[r][t - WLO] : 0.0f;
            float dmu = s_muc[r] - Tval(t);
            float e = fmaxf(1.0f + f - s_negth1[r] * dmu * dmu, 1e-8f);
            float w = Hf; if (t == 0 || t == DXN - 1) w *= 0.5f;
            dw = e * w;
            s_dwf[r][t] = dw;
        }
        unsigned short h = bf16_rne(dw);
        sAh[r * AP + t] = h;
        sAl[r * AP + t] = bf16_rne(dw - bf16_to_f(h));
    }
    __syncthreads();

    // ---- Phase 5: Z per row (first 64 lanes; other waves proceed to GEMM) ----
    if (tid < RS) {
        float z = 0.0f;
        const float* dp = s_dwf[tid];
        #pragma unroll 5
        for (int t = 0; t < DXN; t += 4)
            z += (dp[t] + dp[t + 1]) + (dp[t + 2] + dp[t + 3]);
        s_invZ[tid] = 1.0f / z;
    }

    // ---- Phase 6: MFMA GEMM. wave w: m-tile = w&3 (16 rows), col-half = w>>2 (64 cols) ----
    const int lane = tid & 63;
    const int wv   = tid >> 6;
    const int mt   = wv & 3;
    const int ch   = wv >> 2;
    const int lrow = lane & 15;
    const int kg   = (lane >> 4) * 8;

    short8 Ah[4], Al[4];
    #pragma unroll
    for (int ks = 0; ks < 4; ++ks) {
        Ah[ks] = *(const short8*)&sAh[(mt * 16 + lrow) * AP + ks * 32 + kg];
        Al[ks] = *(const short8*)&sAl[(mt * 16 + lrow) * AP + ks * 32 + kg];
    }
    f32x4 acc[4];
    #pragma unroll
    for (int ct = 0; ct < 4; ++ct) {
        const int ncol = ch * 64 + ct * 16 + lrow;
        f32x4 a = {0.0f, 0.0f, 0.0f, 0.0f};
        #pragma unroll
        for (int ks = 0; ks < 4; ++ks) {
            short8 b = *(const short8*)&sBh[ncol * AP + ks * 32 + kg];
            a = __builtin_amdgcn_mfma_f32_16x16x32_bf16(Ah[ks], b, a, 0, 0, 0);
            a = __builtin_amdgcn_mfma_f32_16x16x32_bf16(Al[ks], b, a, 0, 0, 0);
        }
        acc[ct] = a;
    }
    __syncthreads();   // s_invZ visible

    // ---- Epilogue ----
    f32x4 iz = *(const f32x4*)&s_invZ[mt * 16 + (lane >> 4) * 4];
    #pragma unroll
    for (int ct = 0; ct < 4; ++ct) {
        int col = c0 + ch * 64 + ct * 16 + lrow;
        #pragma unroll
        for (int j = 0; j < 4; ++j) {
            int row = b0 + mt * 16 + (lane >> 4) * 4 + j;
            if (row < Bn) out[row * NB + col] = acc[ct][j] * iz[j];
        }
    }
}

extern "C" void kernel_launch(void* const* d_in, const int* in_sizes, int n_in,
                              void* d_out, int out_size, void* d_ws, size_t ws_size,
                              hipStream_t stream) {
    const float* theta = (const float*)d_in[0];
    const float* mu    = (const float*)d_in[1];
    const float* sigma = (const float*)d_in[2];
    float* outp = (float*)d_out;

    int Bn = in_sizes[0] / TC;                       // 4096
    int grid = ((Bn + RS - 1) / RS) * 4;             // 64 rowslabs x 4 colslabs = 256
    fused_kernel<<<grid, BT, 0, stream>>>(theta, mu, sigma, outp, Bn);
}

// Round 5
// 16.541 us; speedup vs baseline: 1.4896x; 1.4896x over previous
//
#include <hip/hip_runtime.h>
#include <math.h>

#define NB    512
#define DXN   100
#define MROW  128
#define TC    130
#define G     16     // rows per block
#define BT    512
#define KP    128    // padded K
#define AP    136    // LDS row stride (shorts) for A/B bf16 tiles
#define ALP   132    // LDS row stride (floats) for alpha
#define T0f   (-5.0f)
#define Hf    (10.0f / 99.0f)
#define LOG2E 1.4426950408889634f
#define WLO   42
#define WHI   67
#define WN    (WHI - WLO + 1)   // 26

typedef __attribute__((ext_vector_type(8))) short  short8;
typedef __attribute__((ext_vector_type(4))) float  f32x4;

__device__ __forceinline__ float Tval(int t) { return T0f + Hf * (float)t; }

__device__ __forceinline__ unsigned short bf16_rne(float x) {
    unsigned u = __float_as_uint(x);
    return (unsigned short)((u + 0x7FFF + ((u >> 16) & 1)) >> 16);
}
__device__ __forceinline__ float bf16_to_f(unsigned short h) {
    return __uint_as_float(((unsigned)h) << 16);
}

// ONE kernel, 256 blocks x 512 threads. Block = 16 rows x all 512 cols.
// B (phi) recomputed per block into LDS, overlaying dead alpha/f regions.
__global__ __launch_bounds__(BT) void fused_kernel(
    const float* __restrict__ theta,
    const float* __restrict__ mu,
    const float* __restrict__ sigma,
    float* __restrict__ out, int Bn)
{
    // B tile [NB][AP] shorts = 139264 B; overlays alpha [G][ALP] f32 (8448 B)
    // and f [G][WN] f32 (1664 B) which are dead by the time B is written.
    __shared__ __align__(16) unsigned char u_mem[NB * AP * 2];
    __shared__ unsigned short sAh[G * AP];     // 4352 B
    __shared__ unsigned short sAl[G * AP];     // 4352 B
    __shared__ float s_muc[G], s_negth1[G], s_invZ[G];
    __shared__ float s_zp[G][2];

    float*          s_alpha = (float*)u_mem;                  // [G][ALP]
    float*          s_f     = (float*)(u_mem + G * ALP * 4);  // [G][WN]
    unsigned short* sB      = (unsigned short*)u_mem;         // [NB][AP]

    const int tid = threadIdx.x;
    const int b0  = blockIdx.x * G;

    // phi params for this thread's column (consumed in Phase 5b — long overlap)
    const float mun = mu[tid];
    const float sgn = sigma[tid];

    // ---- Phase 1: stage 16 theta rows (th0/th1 parked in s_muc/s_negth1) ----
    for (int i = tid; i < G * TC; i += BT) {
        int r = i / TC, c = i - r * TC;
        int br = b0 + r; if (br >= Bn) br = Bn - 1;
        float v = theta[br * TC + c];
        if (c >= 2)      s_alpha[r * ALP + c - 2] = v;
        else if (c == 0) s_muc[r] = v;
        else             s_negth1[r] = v;
    }
    __syncthreads();

    // ---- Phase 2a: per-row scalars (concurrent with Phase 3) ----
    if (tid < G) {
        float th1 = s_negth1[tid];           // <= -0.5
        s_muc[tid]    = s_muc[tid] * (-0.5f / th1);
        s_negth1[tid] = -th1;
    }

    // ---- Phase 3: f(r,t) on K-active window, exp2 recurrence w/ exact restarts ----
    if (tid < G * WN) {
        int r = tid / WN;
        int t = WLO + (tid - r * WN);
        float T = Tval(t);
        const float C2 = 50.0f * LOG2E;
        const float dj = 1.0f / 127.0f;
        const float cc = -2.0f * C2 * dj * dj;
        const float* al = s_alpha + r * ALP;
        float f = 0.0f;
        #pragma unroll
        for (int j0 = 0; j0 < MROW; j0 += 16) {
            float d0 = (float)j0 * dj - T;
            float a  = -C2 * d0 * d0;
            float bb = -C2 * dj * (2.0f * d0 + dj);
            #pragma unroll
            for (int q = 0; q < 4; ++q) {
                float4 av = *(const float4*)&al[j0 + 4 * q];
                f += av.x * __builtin_amdgcn_exp2f(a); a += bb; bb += cc;
                f += av.y * __builtin_amdgcn_exp2f(a); a += bb; bb += cc;
                f += av.z * __builtin_amdgcn_exp2f(a); a += bb; bb += cc;
                f += av.w * __builtin_amdgcn_exp2f(a); a += bb; bb += cc;
            }
        }
        s_f[r * WN + (t - WLO)] = f;
    }
    __syncthreads();

    // ---- Phase 4: dw -> A bf16 hi/lo + Z partials via wave shfl-reduce ----
    // task = rd*512 + tid; t = task&127, r = task>>7. Wave wv in round rd covers
    // row rd*4 + (wv>>1), t-half (wv&1)*64. One zp write per wave per round.
    #pragma unroll
    for (int rd = 0; rd < 4; ++rd) {
        int task = rd * BT + tid;
        int t = task & (KP - 1), r = task >> 7;
        float dw = 0.0f;
        if (t < DXN) {
            float f = (t >= WLO && t <= WHI) ? s_f[r * WN + t - WLO] : 0.0f;
            float dmu = s_muc[r] - Tval(t);
            float e = fmaxf(1.0f + f - s_negth1[r] * dmu * dmu, 1e-8f);
            float w = Hf; if (t == 0 || t == DXN - 1) w *= 0.5f;
            dw = e * w;
        }
        unsigned short h = bf16_rne(dw);
        sAh[r * AP + t] = h;
        sAl[r * AP + t] = bf16_rne(dw - bf16_to_f(h));
        float z = dw;
        #pragma unroll
        for (int d = 1; d < 64; d <<= 1) z += __shfl_xor(z, d, 64);
        if ((tid & 63) == 0) s_zp[r][(tid >> 6) & 1] = z;
    }
    __syncthreads();   // s_f/alpha now dead; zp ready

    // ---- Phase 5a: invZ (16 lanes) ----
    if (tid < G) s_invZ[tid] = 1.0f / (s_zp[tid][0] + s_zp[tid][1]);

    // ---- Phase 5b: B = phi bf16, [col][k] k-contig; col = tid, direct eval ----
    {
        const float inv_s = 1.0f / sgn;
        const float scale = 0.3989422804014327f * inv_s;
        const float Lh = 0.5f * LOG2E;
        #pragma unroll
        for (int k0 = 0; k0 < KP; k0 += 8) {
            short8 pk;
            #pragma unroll
            for (int j = 0; j < 8; ++j) {
                int k = k0 + j;
                float p = 0.0f;
                if (k < DXN) {
                    float u = (mun - Tval(k)) * inv_s;
                    p = scale * __builtin_amdgcn_exp2f(-Lh * u * u);
                }
                pk[j] = (short)bf16_rne(p);
            }
            *(short8*)&sB[tid * AP + k0] = pk;
        }
    }
    __syncthreads();

    // ---- Phase 6: MFMA GEMM. Wave wv -> cols [wv*64, wv*64+64) as 4 16-col tiles ----
    const int lane = tid & 63;
    const int wv   = tid >> 6;
    const int lrow = lane & 15;
    const int kg   = (lane >> 4) * 8;

    short8 Ah[4], Al[4];
    #pragma unroll
    for (int ks = 0; ks < 4; ++ks) {
        Ah[ks] = *(const short8*)&sAh[lrow * AP + ks * 32 + kg];
        Al[ks] = *(const short8*)&sAl[lrow * AP + ks * 32 + kg];
    }
    f32x4 acc[4];
    #pragma unroll
    for (int ct = 0; ct < 4; ++ct) {
        const int n = wv * 64 + ct * 16 + lrow;
        f32x4 a = {0.0f, 0.0f, 0.0f, 0.0f};
        #pragma unroll
        for (int ks = 0; ks < 4; ++ks) {
            short8 b = *(const short8*)&sB[n * AP + ks * 32 + kg];
            a = __builtin_amdgcn_mfma_f32_16x16x32_bf16(Ah[ks], b, a, 0, 0, 0);
            a = __builtin_amdgcn_mfma_f32_16x16x32_bf16(Al[ks], b, a, 0, 0, 0);
        }
        acc[ct] = a;
    }

    // ---- Epilogue: out = acc * invZ ----
    f32x4 iz = *(const f32x4*)&s_invZ[(lane >> 4) * 4];
    #pragma unroll
    for (int ct = 0; ct < 4; ++ct) {
        int col = wv * 64 + ct * 16 + lrow;
        #pragma unroll
        for (int j = 0; j < 4; ++j) {
            int row = b0 + (lane >> 4) * 4 + j;
            if (row < Bn) out[row * NB + col] = acc[ct][j] * iz[j];
        }
    }
}

extern "C" void kernel_launch(void* const* d_in, const int* in_sizes, int n_in,
                              void* d_out, int out_size, void* d_ws, size_t ws_size,
                              hipStream_t stream) {
    const float* theta = (const float*)d_in[0];
    const float* mu    = (const float*)d_in[1];
    const float* sigma = (const float*)d_in[2];
    float* outp = (float*)d_out;

    int Bn = in_sizes[0] / TC;                  // 4096
    int grid = (Bn + G - 1) / G;                // 256 blocks -> 1 per CU
    fused_kernel<<<grid, BT, 0, stream>>>(theta, mu, sigma, outp, Bn);
}

// Round 6
// 15.381 us; speedup vs baseline: 1.6019x; 1.0754x over previous
//
#include <hip/hip_runtime.h>
#include <hip/hip_bf16.h>
#include <math.h>

#define NB    512
#define DXN   100
#define MROW  128
#define TC    130
#define G     16     // rows per block
#define BT    512
#define KP    128    // padded K
#define AP    136    // LDS row stride (shorts): 68 words -> 2-way bank groups (free)
#define ALP   132    // LDS row stride (floats) for alpha
#define T0f   (-5.0f)
#define Hf    (10.0f / 99.0f)
#define LOG2E 1.4426950408889634f
#define WLO   42
#define WHI   67
#define WN    26

typedef __attribute__((ext_vector_type(8))) short  short8;
typedef __attribute__((ext_vector_type(4))) float  f32x4;

__device__ __forceinline__ float Tval(int t) { return T0f + Hf * (float)t; }

__device__ __forceinline__ unsigned short f2bf(float x) {
    __hip_bfloat16 b = __float2bfloat16(x);
    unsigned short u; __builtin_memcpy(&u, &b, 2); return u;
}
__device__ __forceinline__ float bf2f(unsigned short h) {
    return __uint_as_float(((unsigned)h) << 16);
}
__device__ __forceinline__ unsigned pk2bf(float lo, float hi) {
    __hip_bfloat162 b2 = __float22bfloat162_rn(float2{lo, hi});
    unsigned u; __builtin_memcpy(&u, &b2, 4); return u;
}

// ONE kernel, 256 blocks x 512 threads. Block = 16 rows x all 512 cols.
// Order: phi(B) first (overlaps theta HBM latency), then f, dw, GEMM.
__global__ __launch_bounds__(BT) void fused_kernel(
    const float* __restrict__ theta,
    const float* __restrict__ mu,
    const float* __restrict__ sigma,
    float* __restrict__ out, int Bn)
{
    __shared__ unsigned short sB[NB * AP];                // 139264 B
    __shared__ float s_alpha[G * ALP];                    // 8448 B
    __shared__ float s_f[G * 32];                         // 2048 B
    __shared__ unsigned short sAh[G * AP];                // 4352 B
    __shared__ unsigned short sAl[G * AP];                // 4352 B
    __shared__ __align__(16) float s_muc[G];
    __shared__ __align__(16) float s_negth1[G];
    __shared__ __align__(16) float s_invZ[G];
    __shared__ float s_zp[G][2];                          // total ~158.9 KB

    const int tid = threadIdx.x;
    const int b0  = blockIdx.x * G;

    // ---- issue all global loads up front (phi params + theta chunk) ----
    const float mun = mu[tid];
    const float sgn = sigma[tid];
    float tv[5];
    #pragma unroll
    for (int k = 0; k < 5; ++k) {
        int i = tid + k * BT;
        int r = i / TC, c = i - r * TC;
        int br = b0 + r; if (br >= Bn) br = Bn - 1;
        tv[k] = (i < G * TC) ? theta[br * TC + c] : 0.0f;
    }

    // ---- Phase 0: B = phi bf16 [col][k], exp2 recurrence w/ restart every 16 ----
    {
        const float inv_s = 1.0f / sgn;
        const float dlt = Hf * inv_s;
        const float Lh  = 0.5f * LOG2E;
        const float cc  = -2.0f * Lh * dlt * dlt;
        const float S   = __log2f(0.3989422804014327f * inv_s);  // fold scale into exp
        unsigned short* myB = &sB[tid * AP];
        #pragma unroll
        for (int k0 = 0; k0 < KP; k0 += 16) {
            float u  = (mun - Tval(k0)) * inv_s;
            float a  = S - Lh * u * u;
            float bb = Lh * dlt * (2.0f * u - dlt);
            unsigned w[8];
            #pragma unroll
            for (int j = 0; j < 8; ++j) {
                int k = k0 + 2 * j;
                float p0 = __builtin_amdgcn_exp2f(a); a += bb; bb += cc;
                float p1 = __builtin_amdgcn_exp2f(a); a += bb; bb += cc;
                if (k     >= DXN) p0 = 0.0f;
                if (k + 1 >= DXN) p1 = 0.0f;
                w[j] = pk2bf(p0, p1);
            }
            *(uint4*)&myB[k0]     = make_uint4(w[0], w[1], w[2], w[3]);
            *(uint4*)&myB[k0 + 8] = make_uint4(w[4], w[5], w[6], w[7]);
        }
    }

    // ---- Phase 1: theta regs -> LDS ----
    #pragma unroll
    for (int k = 0; k < 5; ++k) {
        int i = tid + k * BT;
        if (i < G * TC) {
            int r = i / TC, c = i - r * TC;
            if (c >= 2)      s_alpha[r * ALP + c - 2] = tv[k];
            else if (c == 0) s_muc[r] = tv[k];
            else             s_negth1[r] = tv[k];
        }
    }
    __syncthreads();

    // ---- Phase 2a: per-row scalars ----
    if (tid < G) {
        float th1 = s_negth1[tid];            // <= -0.5
        s_muc[tid]    = s_muc[tid] * (-0.5f / th1);
        s_negth1[tid] = -th1;
    }

    // ---- Phase 3: f(r,t), K-active window. r = tid&15 so a wave's ds_read_b128
    //      covers 16 distinct alpha rows (full LDS width, 2-way groups = free) ----
    {
        const int r3 = tid & 15;
        const int tq = tid >> 4;
        if (tq < WN) {
            int t = WLO + tq;
            float T = Tval(t);
            const float C2 = 50.0f * LOG2E;
            const float dj = 1.0f / 127.0f;
            const float cc = -2.0f * C2 * dj * dj;
            const float* al = s_alpha + r3 * ALP;
            float f = 0.0f;
            #pragma unroll
            for (int j0 = 0; j0 < MROW; j0 += 16) {
                float d0 = (float)j0 * dj - T;
                float a  = -C2 * d0 * d0;
                float bb = -C2 * dj * (2.0f * d0 + dj);
                #pragma unroll
                for (int q = 0; q < 4; ++q) {
                    float4 av = *(const float4*)&al[j0 + 4 * q];
                    f += av.x * __builtin_amdgcn_exp2f(a); a += bb; bb += cc;
                    f += av.y * __builtin_amdgcn_exp2f(a); a += bb; bb += cc;
                    f += av.z * __builtin_amdgcn_exp2f(a); a += bb; bb += cc;
                    f += av.w * __builtin_amdgcn_exp2f(a); a += bb; bb += cc;
                }
            }
            s_f[r3 * 32 + tq] = f;
        }
    }
    __syncthreads();

    // ---- Phase 4: dw -> A bf16 hi/lo + Z partials via wave shfl-reduce ----
    #pragma unroll
    for (int rd = 0; rd < 4; ++rd) {
        int task = rd * BT + tid;
        int t = task & (KP - 1), r = task >> 7;
        float dw = 0.0f;
        if (t < DXN) {
            float f = (t >= WLO && t <= WHI) ? s_f[r * 32 + t - WLO] : 0.0f;
            float dmu = s_muc[r] - Tval(t);
            float e = fmaxf(1.0f + f - s_negth1[r] * dmu * dmu, 1e-8f);
            float w = Hf; if (t == 0 || t == DXN - 1) w *= 0.5f;
            dw = e * w;
        }
        unsigned short h = f2bf(dw);
        sAh[r * AP + t] = h;
        sAl[r * AP + t] = f2bf(dw - bf2f(h));
        float z = dw;
        #pragma unroll
        for (int d = 1; d < 64; d <<= 1) z += __shfl_xor(z, d, 64);
        if ((tid & 63) == 0) s_zp[r][(tid >> 6) & 1] = z;
    }
    __syncthreads();

    // ---- Phase 5a: invZ (16 lanes, concurrent with GEMM of other waves) ----
    if (tid < G) s_invZ[tid] = 1.0f / (s_zp[tid][0] + s_zp[tid][1]);

    // ---- Phase 6: MFMA GEMM. Wave wv -> cols [wv*64, wv*64+64) ----
    const int lane = tid & 63;
    const int wv   = tid >> 6;
    const int lrow = lane & 15;
    const int kg   = (lane >> 4) * 8;

    short8 Ah[4], Al[4];
    #pragma unroll
    for (int ks = 0; ks < 4; ++ks) {
        Ah[ks] = *(const short8*)&sAh[lrow * AP + ks * 32 + kg];
        Al[ks] = *(const short8*)&sAl[lrow * AP + ks * 32 + kg];
    }
    f32x4 acc[4];
    #pragma unroll
    for (int ct = 0; ct < 4; ++ct) {
        const int n = wv * 64 + ct * 16 + lrow;
        f32x4 a = {0.0f, 0.0f, 0.0f, 0.0f};
        #pragma unroll
        for (int ks = 0; ks < 4; ++ks) {
            short8 b = *(const short8*)&sB[n * AP + ks * 32 + kg];
            a = __builtin_amdgcn_mfma_f32_16x16x32_bf16(Ah[ks], b, a, 0, 0, 0);
            a = __builtin_amdgcn_mfma_f32_16x16x32_bf16(Al[ks], b, a, 0, 0, 0);
        }
        acc[ct] = a;
    }
    __syncthreads();   // order s_invZ writes before epilogue reads

    // ---- Epilogue: out = acc * invZ ----
    f32x4 iz = *(const f32x4*)&s_invZ[(lane >> 4) * 4];
    #pragma unroll
    for (int ct = 0; ct < 4; ++ct) {
        int col = wv * 64 + ct * 16 + lrow;
        #pragma unroll
        for (int j = 0; j < 4; ++j) {
            int row = b0 + (lane >> 4) * 4 + j;
            if (row < Bn) out[row * NB + col] = acc[ct][j] * iz[j];
        }
    }
}

extern "C" void kernel_launch(void* const* d_in, const int* in_sizes, int n_in,
                              void* d_out, int out_size, void* d_ws, size_t ws_size,
                              hipStream_t stream) {
    const float* theta = (const float*)d_in[0];
    const float* mu    = (const float*)d_in[1];
    const float* sigma = (const float*)d_in[2];
    float* outp = (float*)d_out;

    int Bn = in_sizes[0] / TC;                  // 4096
    int grid = (Bn + G - 1) / G;                // 256 blocks -> 1 per CU
    fused_kernel<<<grid, BT, 0, stream>>>(theta, mu, sigma, outp, Bn);
}

// Round 7
// 13.021 us; speedup vs baseline: 1.8923x; 1.1813x over previous
//
#include <hip/hip_runtime.h>
#include <hip/hip_bf16.h>
#include <math.h>

#define NB    512
#define DXN   100
#define MROW  128
#define TC    130
#define G     16     // rows per block
#define BT    512
#define KP    128    // padded K
#define AP    136    // LDS row stride (shorts)
#define T0f   (-5.0f)
#define Hf    (10.0f / 99.0f)
#define LOG2E 1.4426950408889634f
#define WLO   42     // K-active t-window start; s_f covers t in [42, 74)

typedef __attribute__((ext_vector_type(8))) short  short8;
typedef __attribute__((ext_vector_type(4))) float  f32x4;

__device__ __forceinline__ float Tval(int t) { return T0f + Hf * (float)t; }

__device__ __forceinline__ unsigned short f2bf(float x) {
    __hip_bfloat16 b = __float2bfloat16(x);
    unsigned short u; __builtin_memcpy(&u, &b, 2); return u;
}
__device__ __forceinline__ float bf2f(unsigned short h) {
    return __uint_as_float(((unsigned)h) << 16);
}
__device__ __forceinline__ unsigned pk2bf(float lo, float hi) {
    __hip_bfloat162 b2 = __float22bfloat162_rn(float2{lo, hi});
    unsigned u; __builtin_memcpy(&u, &b2, 4); return u;
}

// ONE kernel, 256 blocks x 512 threads. Block = 16 rows x all 512 cols.
// All contractions on MFMA: f = alpha@K (K-frags in registers), Z = dw@ones,
// out = dw@phi. phi(B) first (overlaps theta HBM latency).
__global__ __launch_bounds__(BT) void fused_kernel(
    const float* __restrict__ theta,
    const float* __restrict__ mu,
    const float* __restrict__ sigma,
    float* __restrict__ out, int Bn)
{
    __shared__ __align__(16) unsigned short sB[NB * AP];     // 139264 B
    __shared__ __align__(16) unsigned short sAlH[G * AP];    // alpha hi
    __shared__ __align__(16) unsigned short sAlL[G * AP];    // alpha lo
    __shared__ __align__(16) unsigned short sAh[G * AP];     // dw hi
    __shared__ __align__(16) unsigned short sAl[G * AP];     // dw lo
    __shared__ float s_f[G * 32];                            // f, t-42 in [0,32)
    __shared__ __align__(16) float s_muc[G];
    __shared__ __align__(16) float s_negth1[G];
    __shared__ __align__(16) float s_invZ[G];                // total 158,912 B

    const int tid  = threadIdx.x;
    const int b0   = blockIdx.x * G;
    const int lane = tid & 63;
    const int wv   = tid >> 6;
    const int lrow = lane & 15;
    const int kg   = (lane >> 4) * 8;

    // ---- issue all global loads up front ----
    const float mun = mu[tid];
    const float sgn = sigma[tid];
    float tv[5];
    #pragma unroll
    for (int k = 0; k < 5; ++k) {
        int i = tid + k * BT;
        int r = i / TC, c = i - r * TC;
        int br = b0 + r; if (br >= Bn) br = Bn - 1;
        tv[k] = (i < G * TC) ? theta[br * TC + c] : 0.0f;
    }

    // ---- Phase 0: B = phi bf16 [col][k], exp2 recurrence, restart every 16 ----
    {
        const float inv_s = 1.0f / sgn;
        const float dlt = Hf * inv_s;
        const float Lh  = 0.5f * LOG2E;
        const float cc  = -2.0f * Lh * dlt * dlt;
        const float S   = __log2f(0.3989422804014327f * inv_s);
        unsigned short* myB = &sB[tid * AP];
        #pragma unroll
        for (int k0 = 0; k0 < 96; k0 += 16) {
            float u  = (mun - Tval(k0)) * inv_s;
            float a  = S - Lh * u * u;
            float bb = Lh * dlt * (2.0f * u - dlt);
            unsigned w[8];
            #pragma unroll
            for (int j = 0; j < 8; ++j) {
                float p0 = __builtin_amdgcn_exp2f(a); a += bb; bb += cc;
                float p1 = __builtin_amdgcn_exp2f(a); a += bb; bb += cc;
                w[j] = pk2bf(p0, p1);
            }
            *(uint4*)&myB[k0]     = make_uint4(w[0], w[1], w[2], w[3]);
            *(uint4*)&myB[k0 + 8] = make_uint4(w[4], w[5], w[6], w[7]);
        }
        {   // k = 96..99 real, 100..127 zero pad
            float u  = (mun - Tval(96)) * inv_s;
            float a  = S - Lh * u * u;
            float bb = Lh * dlt * (2.0f * u - dlt);
            float p0 = __builtin_amdgcn_exp2f(a); a += bb; bb += cc;
            float p1 = __builtin_amdgcn_exp2f(a); a += bb; bb += cc;
            unsigned w0 = pk2bf(p0, p1);
            p0 = __builtin_amdgcn_exp2f(a); a += bb; bb += cc;
            p1 = __builtin_amdgcn_exp2f(a);
            unsigned w1 = pk2bf(p0, p1);
            *(uint4*)&myB[96]  = make_uint4(w0, w1, 0u, 0u);
            *(uint4*)&myB[104] = make_uint4(0u, 0u, 0u, 0u);
            *(uint4*)&myB[112] = make_uint4(0u, 0u, 0u, 0u);
            *(uint4*)&myB[120] = make_uint4(0u, 0u, 0u, 0u);
        }
    }

    // ---- Phase 1: theta -> alpha bf16 hi/lo + raw th0/th1 ----
    #pragma unroll
    for (int k = 0; k < 5; ++k) {
        int i = tid + k * BT;
        if (i < G * TC) {
            int r = i / TC, c = i - r * TC;
            float v = tv[k];
            if (c >= 2) {
                unsigned short h = f2bf(v);
                sAlH[r * AP + (c - 2)] = h;
                sAlL[r * AP + (c - 2)] = f2bf(v - bf2f(h));
            } else if (c == 0) s_muc[r] = v;
            else               s_negth1[r] = v;
        }
    }
    __syncthreads();

    // ---- Phase 2a: per-row scalars (lanes 0..15 of wave 0) ----
    if (tid < G) {
        float th1 = s_negth1[tid];            // <= -0.5
        s_muc[tid]    = s_muc[tid] * (-0.5f / th1);
        s_negth1[tid] = -th1;
    }

    // ---- Phase 2b: f = alpha @ K via MFMA; waves 0,1; K-frags in registers ----
    if (wv < 2) {
        const int tcol = WLO + wv * 16 + lrow;
        const float T  = Tval(tcol);
        const float C2 = 50.0f * LOG2E;
        const float dj = 1.0f / 127.0f;
        f32x4 fa = {0.0f, 0.0f, 0.0f, 0.0f};
        #pragma unroll
        for (int ks = 0; ks < 4; ++ks) {
            short8 ah = *(const short8*)&sAlH[lrow * AP + ks * 32 + kg];
            short8 al = *(const short8*)&sAlL[lrow * AP + ks * 32 + kg];
            short8 kh, kl;
            #pragma unroll
            for (int jj = 0; jj < 8; ++jj) {
                float d  = (float)(ks * 32 + kg + jj) * dj - T;
                float kv = __builtin_amdgcn_exp2f(-C2 * d * d);
                unsigned short h = f2bf(kv);
                kh[jj] = (short)h;
                kl[jj] = (short)f2bf(kv - bf2f(h));
            }
            fa = __builtin_amdgcn_mfma_f32_16x16x32_bf16(ah, kh, fa, 0, 0, 0);
            fa = __builtin_amdgcn_mfma_f32_16x16x32_bf16(al, kh, fa, 0, 0, 0);
            fa = __builtin_amdgcn_mfma_f32_16x16x32_bf16(ah, kl, fa, 0, 0, 0);
        }
        #pragma unroll
        for (int j = 0; j < 4; ++j)
            s_f[((lane >> 4) * 4 + j) * 32 + wv * 16 + lrow] = fa[j];
    }
    __syncthreads();

    // ---- Phase 3: dw -> A bf16 hi/lo. Wave wv, round rd owns row rd*8+wv;
    //      lane handles t = 2*lane, 2*lane+1 (pack via cvt_pk pairs) ----
    #pragma unroll
    for (int rd = 0; rd < 2; ++rd) {
        const int row = rd * 8 + wv;
        const float muc = s_muc[row], nth = s_negth1[row];
        const int t0 = 2 * lane;
        float dw0 = 0.0f, dw1 = 0.0f;
        if (t0 < DXN) {
            unsigned i0 = (unsigned)(t0 - WLO);
            float f0 = (i0 < 32u) ? s_f[row * 32 + i0] : 0.0f;
            float dm0 = muc - Tval(t0);
            float e0 = fmaxf(1.0f + f0 - nth * dm0 * dm0, 1e-8f);
            dw0 = e0 * ((t0 == 0) ? Hf * 0.5f : Hf);
            const int t1 = t0 + 1;                       // <= 99
            unsigned i1 = (unsigned)(t1 - WLO);
            float f1 = (i1 < 32u) ? s_f[row * 32 + i1] : 0.0f;
            float dm1 = muc - Tval(t1);
            float e1 = fmaxf(1.0f + f1 - nth * dm1 * dm1, 1e-8f);
            dw1 = e1 * ((t1 == DXN - 1) ? Hf * 0.5f : Hf);
        }
        unsigned short h0 = f2bf(dw0), h1 = f2bf(dw1);
        unsigned short l0 = f2bf(dw0 - bf2f(h0)), l1 = f2bf(dw1 - bf2f(h1));
        ((unsigned*)sAh)[row * (AP / 2) + lane] = ((unsigned)h1 << 16) | h0;
        ((unsigned*)sAl)[row * (AP / 2) + lane] = ((unsigned)l1 << 16) | l0;
    }
    __syncthreads();

    // ---- Phase 4: MFMA GEMM (out) + Z via ones-MFMA on wave 0 ----
    short8 Ah[4], Al[4];
    #pragma unroll
    for (int ks = 0; ks < 4; ++ks) {
        Ah[ks] = *(const short8*)&sAh[lrow * AP + ks * 32 + kg];
        Al[ks] = *(const short8*)&sAl[lrow * AP + ks * 32 + kg];
    }
    f32x4 acc[4];
    #pragma unroll
    for (int ct = 0; ct < 4; ++ct) {
        const int n = wv * 64 + ct * 16 + lrow;
        f32x4 a = {0.0f, 0.0f, 0.0f, 0.0f};
        #pragma unroll
        for (int ks = 0; ks < 4; ++ks) {
            short8 b = *(const short8*)&sB[n * AP + ks * 32 + kg];
            a = __builtin_amdgcn_mfma_f32_16x16x32_bf16(Ah[ks], b, a, 0, 0, 0);
            a = __builtin_amdgcn_mfma_f32_16x16x32_bf16(Al[ks], b, a, 0, 0, 0);
        }
        acc[ct] = a;
    }
    if (wv == 0) {
        short8 ones;
        #pragma unroll
        for (int jj = 0; jj < 8; ++jj) ones[jj] = (short)0x3F80;   // bf16 1.0
        f32x4 az = {0.0f, 0.0f, 0.0f, 0.0f};
        #pragma unroll
        for (int ks = 0; ks < 4; ++ks) {
            az = __builtin_amdgcn_mfma_f32_16x16x32_bf16(Ah[ks], ones, az, 0, 0, 0);
            az = __builtin_amdgcn_mfma_f32_16x16x32_bf16(Al[ks], ones, az, 0, 0, 0);
        }
        if ((lane & 15) == 0) {
            #pragma unroll
            for (int j = 0; j < 4; ++j)
                s_invZ[(lane >> 4) * 4 + j] = 1.0f / az[j];
        }
    }
    __syncthreads();

    // ---- Epilogue: out = acc * invZ ----
    f32x4 iz = *(const f32x4*)&s_invZ[(lane >> 4) * 4];
    #pragma unroll
    for (int ct = 0; ct < 4; ++ct) {
        int col = wv * 64 + ct * 16 + lrow;
        #pragma unroll
        for (int j = 0; j < 4; ++j) {
            int row = b0 + (lane >> 4) * 4 + j;
            if (row < Bn) out[row * NB + col] = acc[ct][j] * iz[j];
        }
    }
}

extern "C" void kernel_launch(void* const* d_in, const int* in_sizes, int n_in,
                              void* d_out, int out_size, void* d_ws, size_t ws_size,
                              hipStream_t stream) {
    const float* theta = (const float*)d_in[0];
    const float* mu    = (const float*)d_in[1];
    const float* sigma = (const float*)d_in[2];
    float* outp = (float*)d_out;

    int Bn = in_sizes[0] / TC;                  // 4096
    int grid = (Bn + G - 1) / G;                // 256 blocks -> 1 per CU
    fused_kernel<<<grid, BT, 0, stream>>>(theta, mu, sigma, outp, Bn);
}